// Round 2
// baseline (224.579 us; speedup 1.0000x reference)
//
#include <hip/hip_runtime.h>

#define NP 15
#define NK 17
#define HH 256
#define WW 256

#define TPB 256
#define UNROLL 8
#define BLOCKS 2040   // 2040*256*8 = 4,177,920 = NP*NK*HH*WW/4 exactly (no tail)

// ws layout: ws[0]=softplus sum (double), ws[1]=weighted disk sum (double),
//            then a 4-byte completion counter.
__global__ __launch_bounds__(256) void fused_loss_kernel(
    const float4* __restrict__ x4, const float* __restrict__ pred,
    const float* __restrict__ kp, double* __restrict__ ws,
    unsigned int* __restrict__ wcount, float* __restrict__ out) {
    const int tid = threadIdx.x;

    // ---- streaming softplus: 8 independent coalesced float4 loads ----
    size_t base = (size_t)blockIdx.x * (TPB * UNROLL) + tid;
    float4 v[UNROLL];
    #pragma unroll
    for (int k = 0; k < UNROLL; ++k) v[k] = x4[base + (size_t)k * TPB];

    float acc = 0.f;
    #pragma unroll
    for (int k = 0; k < UNROLL; ++k) {
        acc += fmaxf(v[k].x, 0.f) + __logf(1.f + __expf(-fabsf(v[k].x)));
        acc += fmaxf(v[k].y, 0.f) + __logf(1.f + __expf(-fabsf(v[k].y)));
        acc += fmaxf(v[k].z, 0.f) + __logf(1.f + __expf(-fabsf(v[k].z)));
        acc += fmaxf(v[k].w, 0.f) + __logf(1.f + __expf(-fabsf(v[k].w)));
    }

    // ---- keypoint disk sum: blocks 0..254, wave 0 only (one masked load) ----
    float dsum = 0.f;
    if (blockIdx.x < NP * NK && tid < 64) {
        const int t = blockIdx.x;          // keypoint index (p*NK + k)
        const float xf = kp[2 * t];
        const float yf = kp[2 * t + 1];
        const bool valid =
            ((xf != 0.f) && (xf != -1.f)) || ((yf != 0.f) && (yf != -1.f));
        if (valid && tid < 49) {
            const int dy = tid / 7 - 3;
            const int dx = tid % 7 - 3;
            if (dy * dy + dx * dx <= 9) {
                const int yy = (int)yf + dy;   // truncation matches astype(int32)
                const int xx = (int)xf + dx;
                if (yy >= 0 && yy < HH && xx >= 0 && xx < WW)
                    dsum = pred[(size_t)t * (HH * WW) + yy * WW + xx];
            }
        }
        #pragma unroll
        for (int off = 32; off > 0; off >>= 1)
            dsum += __shfl_down(dsum, off, 64);
        if (tid == 0) {
            const int p = t / NK;
            dsum *= (float)(NP - p);
        }
    }

    // ---- block reduce of softplus partial ----
    #pragma unroll
    for (int off = 32; off > 0; off >>= 1)
        acc += __shfl_down(acc, off, 64);
    __shared__ float wsums[4];
    if ((tid & 63) == 0) wsums[tid >> 6] = acc;
    __syncthreads();

    if (tid == 0) {
        float btot = wsums[0] + wsums[1] + wsums[2] + wsums[3];
        atomicAdd(&ws[0], (double)btot);
        if (blockIdx.x < NP * NK) atomicAdd(&ws[1], (double)dsum);
        __threadfence();
        unsigned int old = atomicAdd(wcount, 1u);
        if (old == BLOCKS - 1) {
            // last block: read accumulators at the coherent point and combine
            double ssum = atomicAdd(&ws[0], 0.0);
            double wsum = atomicAdd(&ws[1], 0.0);
            const double N = (double)NP * NK * HH * WW;
            double heatmap_loss = ssum / N - wsum / ((double)NP * N);
            out[0] = (float)(4.0 * heatmap_loss + 0.02);
        }
    }
}

extern "C" void kernel_launch(void* const* d_in, const int* in_sizes, int n_in,
                              void* d_out, int out_size, void* d_ws, size_t ws_size,
                              hipStream_t stream) {
    const float* pred = (const float*)d_in[0];   // [15,17,256,256] fp32
    const float* kp   = (const float*)d_in[2];   // [15,17,2] fp32
    float* out = (float*)d_out;
    double* ws = (double*)d_ws;
    unsigned int* wcount = (unsigned int*)(ws + 2);

    // ws is re-poisoned to 0xAA before every timed call — zero the 24 bytes we use.
    hipMemsetAsync(d_ws, 0, 24, stream);

    fused_loss_kernel<<<BLOCKS, TPB, 0, stream>>>(
        (const float4*)pred, pred, kp, ws, wcount, out);
}